// Round 10
// baseline (695.268 us; speedup 1.0000x reference)
//
#include <hip/hip_runtime.h>

typedef __attribute__((ext_vector_type(8))) short short8;
typedef __attribute__((ext_vector_type(4))) short short4v;
typedef __attribute__((ext_vector_type(4))) float floatx4;
typedef unsigned int u32;

#define CC 256
#define NN 4096
#define NB 8

static __device__ __forceinline__ float b2f(ushort u) {
    union { unsigned int i; float f; } c;
    c.i = ((unsigned int)u) << 16;
    return c.f;
}

static __device__ __forceinline__ ushort f2bf(float f) {
    union { float f; unsigned int u; } c;
    c.f = f;
    unsigned int u = c.u;
    u += 0x7fffu + ((u >> 16) & 1u);
    return (ushort)(u >> 16);
}

static __device__ __forceinline__ short8 load8(const void* p, size_t idx, bool isbf) {
    if (isbf) {
        return *(const short8*)((const ushort*)p + idx);
    } else {
        const float* f = (const float*)p + idx;
        floatx4 a = *(const floatx4*)f;
        floatx4 b = *(const floatx4*)(f + 4);
        short8 r;
        #pragma unroll
        for (int j = 0; j < 4; j++) {
            ((ushort*)&r)[j]     = f2bf(a[j]);
            ((ushort*)&r)[j + 4] = f2bf(b[j]);
        }
        return r;
    }
}

static __device__ __forceinline__ float loadS(const void* p, size_t idx, bool isbf) {
    return isbf ? b2f(((const ushort*)p)[idx]) : ((const float*)p)[idx];
}

static __device__ __forceinline__ bool detect_bf16(const void* x) {
    const ushort* xu = (const ushort*)x;
    int cnt = 0;
    #pragma unroll
    for (int j = 0; j < 8; j++) {
        ushort u = xu[(size_t)j * 1048576];
        int e = (u >> 7) & 0xFF;
        cnt += ((e >= 100 && e <= 141) || (u & 0x7FFF) == 0) ? 1 : 0;
    }
    return cnt >= 7;
}

// async global -> LDS, 16B per lane; LDS dest is wave-uniform base (+lane*16B)
static __device__ __forceinline__ void gll16(const ushort* g, ushort* l) {
    __builtin_amdgcn_global_load_lds(
        (const __attribute__((address_space(1))) u32*)g,
        (__attribute__((address_space(3))) u32*)l, 16, 0, 0);
}

// -------------------------------------------------------------------------
// projkvpq: one 64x64 tile of K, V, P, AND Q from a single x staging pass.
//   K -> k_ws bf16 [bl][N][C];  V -> v_ws bf16 [bl][C][N];
//   P -> out fp32 [b][C][N];    Q -> q_ws bf16 [bl][N][C], scaled C^-0.5.
// grid (NN/64, CC/64, BC), block 256 (4 waves). LDS 34816 B.
// -------------------------------------------------------------------------
__global__ __launch_bounds__(256) void projkvpq(
    const void* __restrict__ x,
    const void* __restrict__ Wk, const void* __restrict__ bk,
    const void* __restrict__ Wv, const void* __restrict__ bv,
    const void* __restrict__ Wp, const void* __restrict__ bp,
    const void* __restrict__ Wq, const void* __restrict__ bq,
    ushort* __restrict__ k_ws, ushort* __restrict__ v_ws,
    ushort* __restrict__ q_ws, float* __restrict__ out, int b0)
{
    __shared__ __align__(16) ushort A_lds[4][64 * 40];
    __shared__ __align__(16) ushort Bt_lds[64 * 40];
    __shared__ __align__(16) ushort T_lds[64 * 72];

    const bool isbf = detect_bf16(x);
    const int tid  = threadIdx.x;
    const int wave = tid >> 6;
    const int lane = tid & 63;
    const int l16  = lane & 15;
    const int quad = lane >> 4;

    const int n0 = blockIdx.x * 64;
    const int o0 = blockIdx.y * 64;
    const int bl = blockIdx.z;
    const int b  = b0 + bl;

    floatx4 zero4 = {0.f, 0.f, 0.f, 0.f};
    floatx4 acc[4][4];
    #pragma unroll
    for (int w = 0; w < 4; w++)
        #pragma unroll
        for (int t = 0; t < 4; t++) acc[w][t] = zero4;

    const void* Ws[4] = {Wk, Wv, Wp, Wq};

    for (int k0 = 0; k0 < CC; k0 += 32) {
        __syncthreads();
        {   // A[w] = W_w[o0..+64)[k0..+32)
            int row = tid >> 2, c8 = (tid & 3) * 8;
            #pragma unroll
            for (int w = 0; w < 4; w++)
                *(short8*)&A_lds[w][row * 40 + c8] =
                    load8(Ws[w], (size_t)(o0 + row) * CC + k0 + c8, isbf);
        }
        {   // Bt = x[k0..+32)[n0..+64) transposed -> [n][c]
            int c = tid >> 3, n8 = (tid & 7) * 8;
            short8 xv = load8(x, ((size_t)b * CC + k0 + c) * NN + n0 + n8, isbf);
            #pragma unroll
            for (int j = 0; j < 8; j++)
                Bt_lds[(n8 + j) * 40 + c] = ((ushort*)&xv)[j];
        }
        __syncthreads();

        short8 af[4];
        #pragma unroll
        for (int w = 0; w < 4; w++)
            af[w] = *(const short8*)&A_lds[w][(wave * 16 + l16) * 40 + quad * 8];
        #pragma unroll
        for (int t = 0; t < 4; t++) {
            short8 bf = *(const short8*)&Bt_lds[(t * 16 + l16) * 40 + quad * 8];
            #pragma unroll
            for (int w = 0; w < 4; w++)
                acc[w][t] = __builtin_amdgcn_mfma_f32_16x16x32_bf16(af[w], bf, acc[w][t], 0, 0, 0);
        }
    }

    float biasv[4][4];
    const void* Bs[4] = {bk, bv, bp, bq};
    #pragma unroll
    for (int w = 0; w < 4; w++)
        #pragma unroll
        for (int r = 0; r < 4; r++)
            biasv[w][r] = loadS(Bs[w], (size_t)(o0 + wave * 16 + quad * 4 + r), isbf);

    // ---- K epilogue: T[n][o], store [bl][n][C] ----
    __syncthreads();
    #pragma unroll
    for (int t = 0; t < 4; t++)
        #pragma unroll
        for (int r = 0; r < 4; r++)
            T_lds[(t * 16 + l16) * 72 + wave * 16 + quad * 4 + r] =
                f2bf(acc[0][t][r] + biasv[0][r]);
    __syncthreads();
    for (int u = tid; u < 512; u += 256) {
        int n = u >> 3, o8 = (u & 7) * 8;
        *(short8*)&k_ws[((size_t)bl * NN + n0 + n) * CC + o0 + o8] =
            *(const short8*)&T_lds[n * 72 + o8];
    }

    // ---- Q epilogue: T[n][o] scaled, store [bl][n][C] ----
    __syncthreads();
    #pragma unroll
    for (int t = 0; t < 4; t++)
        #pragma unroll
        for (int r = 0; r < 4; r++)
            T_lds[(t * 16 + l16) * 72 + wave * 16 + quad * 4 + r] =
                f2bf((acc[3][t][r] + biasv[3][r]) * 0.0625f);
    __syncthreads();
    for (int u = tid; u < 512; u += 256) {
        int n = u >> 3, o8 = (u & 7) * 8;
        *(short8*)&q_ws[((size_t)bl * NN + n0 + n) * CC + o0 + o8] =
            *(const short8*)&T_lds[n * 72 + o8];
    }

    // ---- V epilogue: T[o][n], store [bl][C][n] ----
    __syncthreads();
    #pragma unroll
    for (int t = 0; t < 4; t++)
        #pragma unroll
        for (int r = 0; r < 4; r++)
            T_lds[(wave * 16 + quad * 4 + r) * 72 + t * 16 + l16] =
                f2bf(acc[1][t][r] + biasv[1][r]);
    __syncthreads();
    for (int u = tid; u < 512; u += 256) {
        int o = u >> 3, n8 = (u & 7) * 8;
        *(short8*)&v_ws[((size_t)bl * CC + o0 + o) * NN + n0 + n8] =
            *(const short8*)&T_lds[o * 72 + n8];
    }

    // ---- P epilogue: direct fp32 stores ----
    #pragma unroll
    for (int t = 0; t < 4; t++)
        #pragma unroll
        for (int r = 0; r < 4; r++)
            out[((size_t)b * CC + o0 + wave * 16 + quad * 4 + r) * NN +
                n0 + t * 16 + l16] = acc[2][t][r] + biasv[2][r];
}

// -------------------------------------------------------------------------
// attn_mfma v11: v10 flash loop with (a) Q precomputed (no Phase A — 8
// global b128 loads into qf), (b) V read DIRECTLY from L2 into registers
// (no Vt staging: half the gll16/vmcnt drain, 16 fewer LDS reads/iter),
// issued before softmax so L2 latency hides under QK+softmax, (c) K still
// LDS-staged (4-wave reuse). LDS 34816 B. grid (NN/64, BC), block 256.
// -------------------------------------------------------------------------
__global__ __launch_bounds__(256) void attn_mfma(
    const ushort* __restrict__ q_ws, const ushort* __restrict__ k_ws,
    const ushort* __restrict__ v_ws, float* __restrict__ out, int b0)
{
    // Pool: 17408 ushorts = 34816 B (= Tf epilogue size)
    __shared__ __align__(16) ushort lds[17408];
    ushort* K_lds = lds;            // [32][256] swizzled: slot p holds p^(row&7)
    ushort* P_lds = lds + 8192;     // [4][16][40] wave-local
    float*  Tf    = (float*)lds;    // [128][68] fp32 epilogue (aliases)

    const int tid  = threadIdx.x;
    const int wave = tid >> 6;
    const int lane = tid & 63;
    const int l16  = lane & 15;
    const int quad = lane >> 4;
    const int bl = blockIdx.y;
    const int b  = b0 + bl;
    const int n0 = blockIdx.x * 64;

    floatx4 zero4 = {0.f, 0.f, 0.f, 0.f};

    // ---- load Q fragments (bf16, pre-scaled) straight from workspace ----
    const ushort* qp = q_ws + ((size_t)bl * NN + n0 + wave * 16 + l16) * CC;
    short8 qf[8];
    #pragma unroll
    for (int s = 0; s < 8; s++)
        qf[s] = *(const short8*)&qp[s * 32 + quad * 8];

    const ushort* kp = k_ws + (size_t)bl * NN * CC;   // [n][C]
    const ushort* vp = v_ws + (size_t)bl * CC * NN;   // [C][n]

    floatx4 Oacc[16];
    #pragma unroll
    for (int t = 0; t < 16; t++) Oacc[t] = zero4;
    // per-lane softmax state for q-row (wave*16 + l16)
    float mrow = -1e30f, lrow = 0.f;

    #pragma unroll 1
    for (int it = 0; it < NN / 32; ++it) {
        const int m0 = it * 32;
        __syncthreads();   // all waves done reading K_lds/P_lds of prev iter

        // stage K only (16 x 1KB chunks, 4/wave), LDS dest linear,
        // global source pre-swizzled (rule 21: source + read pair)
        #pragma unroll
        for (int i = 0; i < 4; i++) {
            int c = wave * 4 + i;
            int row = c * 2 + (lane >> 5);
            int sw  = (lane & 31) ^ (row & 7);
            gll16(kp + (size_t)(m0 + row) * CC + sw * 8, K_lds + c * 512);
        }
        __syncthreads();   // vmcnt drained: K tile visible

        // QK^T SWAPPED: S[t] = mfma(K, Q): D[key][q-row], lane owns row l16
        floatx4 S[2];
        S[0] = zero4; S[1] = zero4;
        #pragma unroll
        for (int t = 0; t < 2; t++) {
            int row = t * 16 + l16;
            int rsw = row & 7;
            #pragma unroll
            for (int s = 0; s < 8; s++) {
                short8 kf = *(const short8*)&K_lds[row * 256 + ((s * 4 + quad) ^ rsw) * 8];
                S[t] = __builtin_amdgcn_mfma_f32_16x16x32_bf16(kf, qf[s], S[t], 0, 0, 0);
            }
        }

        // V loads direct from L2 into registers (independent of LDS state);
        // issued here so ~latency hides under softmax below.
        short8 vreg[16];
        #pragma unroll
        for (int ct = 0; ct < 16; ct++)
            vreg[ct] = *(const short8*)&vp[(size_t)(ct * 16 + l16) * NN + m0 + quad * 8];

        // online softmax, per-lane row l16: in-lane reduce + 2 shuffles
        float mx = fmaxf(fmaxf(fmaxf(S[0][0], S[0][1]), fmaxf(S[0][2], S[0][3])),
                         fmaxf(fmaxf(S[1][0], S[1][1]), fmaxf(S[1][2], S[1][3])));
        mx = fmaxf(mx, __shfl_xor(mx, 16, 64));
        mx = fmaxf(mx, __shfl_xor(mx, 32, 64));

        if (__any(mx - mrow > 8.0f)) {   // defer-max (T13): rare after warmup
            float mn = fmaxf(mrow, mx);
            float al = __expf(mrow - mn);
            mrow = mn;
            lrow *= al;
            float a[4];
            #pragma unroll
            for (int r = 0; r < 4; r++) a[r] = __shfl(al, quad * 4 + r, 64);
            #pragma unroll
            for (int ct = 0; ct < 16; ct++)
                #pragma unroll
                for (int r = 0; r < 4; r++)
                    Oacc[ct][r] *= a[r];
        }

        // P = exp(S - m), pack to bf16, 2 x ds_write_b64 (wave-local rows)
        short4v w0, w1;
        float rs = 0.f;
        #pragma unroll
        for (int r = 0; r < 4; r++) {
            float p0 = __expf(S[0][r] - mrow);
            float p1 = __expf(S[1][r] - mrow);
            rs += p0 + p1;
            ((ushort*)&w0)[r] = f2bf(p0);
            ((ushort*)&w1)[r] = f2bf(p1);
        }
        rs += __shfl_xor(rs, 16, 64);
        rs += __shfl_xor(rs, 32, 64);
        lrow += rs;
        {   // P_lds[row l16][key]
            int base = wave * 640 + l16 * 40 + quad * 4;
            *(short4v*)&P_lds[base]      = w0;
            *(short4v*)&P_lds[base + 16] = w1;
        }

        // in-wave fence (DS in-order per wave); pin scheduler (rule 18)
        asm volatile("s_waitcnt lgkmcnt(0)" ::: "memory");
        __builtin_amdgcn_sched_barrier(0);

        // PV: O[ct] += P . V(16 ch of ct), one MFMA per ct (k=32)
        short8 pf = *(const short8*)&P_lds[wave * 640 + l16 * 40 + quad * 8];
        #pragma unroll
        for (int ct = 0; ct < 16; ct++)
            Oacc[ct] = __builtin_amdgcn_mfma_f32_16x16x32_bf16(pf, vreg[ct], Oacc[ct], 0, 0, 0);
    }

    // ---- epilogue: out = h/l + P (fp32 RMW), two 128-channel halves ----
    float li = 1.0f / lrow;              // row l16's norm
    float linv[4];
    #pragma unroll
    for (int r = 0; r < 4; r++) linv[r] = __shfl(li, quad * 4 + r, 64);

    #pragma unroll
    for (int h = 0; h < 2; h++) {
        __syncthreads();   // flash LDS dead (or prev half consumed)
        #pragma unroll
        for (int ct = h * 8; ct < h * 8 + 8; ct++)
            #pragma unroll
            for (int r = 0; r < 4; r++)
                Tf[(ct * 16 + l16 - h * 128) * 68 + wave * 16 + quad * 4 + r] =
                    Oacc[ct][r] * linv[r];
        __syncthreads();
        #pragma unroll
        for (int i = 0; i < 8; i++) {
            int u = tid + i * 256;           // 2048 float4 slots = 128ch x 16
            int row = u >> 4, col4 = (u & 15) * 4;
            size_t gi = ((size_t)b * CC + h * 128 + row) * NN + n0 + col4;
            floatx4 pv = *(const floatx4*)&out[gi];
            floatx4 tv = *(const floatx4*)&Tf[row * 68 + col4];
            pv[0] += tv[0]; pv[1] += tv[1]; pv[2] += tv[2]; pv[3] += tv[3];
            *(floatx4*)&out[gi] = pv;
        }
    }
}

// -------------------------------------------------------------------------
extern "C" void kernel_launch(void* const* d_in, const int* in_sizes, int n_in,
                              void* d_out, int out_size, void* d_ws, size_t ws_size,
                              hipStream_t stream) {
    int xi = 0;
    for (int i = 0; i < n_in; i++)
        if (in_sizes[i] == NB * CC * NN) xi = i;

    const void *x, *Wq, *bq, *Wk, *bk, *Wv, *bv, *Wp, *bp;
    if (xi == 0) {
        x  = d_in[0];
        Wq = d_in[1]; bq = d_in[2];
        Wk = d_in[3]; bk = d_in[4];
        Wv = d_in[5]; bv = d_in[6];
        Wp = d_in[7]; bp = d_in[8];
    } else {
        int wi[4], bi[4], nw = 0, nb = 0;
        for (int i = 0; i < n_in; i++) {
            if (i == xi) continue;
            if (in_sizes[i] == CC * CC) { if (nw < 4) wi[nw++] = i; }
            else                        { if (nb < 4) bi[nb++] = i; }
        }
        x  = d_in[xi];
        Wk = d_in[wi[0]]; Wp = d_in[wi[1]]; Wq = d_in[wi[2]]; Wv = d_in[wi[3]];
        bk = d_in[bi[0]]; bp = d_in[bi[1]]; bq = d_in[bi[2]]; bv = d_in[bi[3]];
    }

    float*  out = (float*)d_out;     // fp32 output
    ushort* ws  = (ushort*)d_ws;

    const size_t tsz_b = (size_t)NN * CC;
    int BC = 8;
    while (BC > 1 && (size_t)BC * tsz_b * 2 * 3 > ws_size) BC >>= 1;
    ushort* k_ws = ws;
    ushort* v_ws = ws + (size_t)BC * tsz_b;
    ushort* q_ws = ws + 2 * (size_t)BC * tsz_b;

    for (int c0 = 0; c0 < NB; c0 += BC) {
        projkvpq<<<dim3(NN / 64, CC / 64, BC), dim3(256), 0, stream>>>(
            x, Wk, bk, Wv, bv, Wp, bp, Wq, bq, k_ws, v_ws, q_ws, out, c0);
        attn_mfma<<<dim3(NN / 64, BC), dim3(256), 0, stream>>>(
            q_ws, k_ws, v_ws, out, c0);
    }
}

// Round 11
// 475.028 us; speedup vs baseline: 1.4636x; 1.4636x over previous
//
#include <hip/hip_runtime.h>

typedef __attribute__((ext_vector_type(8))) short short8;
typedef __attribute__((ext_vector_type(4))) short short4v;
typedef __attribute__((ext_vector_type(4))) float floatx4;
typedef unsigned int u32;

#define CC 256
#define NN 4096
#define NB 8

static __device__ __forceinline__ float b2f(ushort u) {
    union { unsigned int i; float f; } c;
    c.i = ((unsigned int)u) << 16;
    return c.f;
}

static __device__ __forceinline__ ushort f2bf(float f) {
    union { float f; unsigned int u; } c;
    c.f = f;
    unsigned int u = c.u;
    u += 0x7fffu + ((u >> 16) & 1u);
    return (ushort)(u >> 16);
}

static __device__ __forceinline__ short8 load8(const void* p, size_t idx, bool isbf) {
    if (isbf) {
        return *(const short8*)((const ushort*)p + idx);
    } else {
        const float* f = (const float*)p + idx;
        floatx4 a = *(const floatx4*)f;
        floatx4 b = *(const floatx4*)(f + 4);
        short8 r;
        #pragma unroll
        for (int j = 0; j < 4; j++) {
            ((ushort*)&r)[j]     = f2bf(a[j]);
            ((ushort*)&r)[j + 4] = f2bf(b[j]);
        }
        return r;
    }
}

static __device__ __forceinline__ float loadS(const void* p, size_t idx, bool isbf) {
    return isbf ? b2f(((const ushort*)p)[idx]) : ((const float*)p)[idx];
}

static __device__ __forceinline__ bool detect_bf16(const void* x) {
    const ushort* xu = (const ushort*)x;
    int cnt = 0;
    #pragma unroll
    for (int j = 0; j < 8; j++) {
        ushort u = xu[(size_t)j * 1048576];
        int e = (u >> 7) & 0xFF;
        cnt += ((e >= 100 && e <= 141) || (u & 0x7FFF) == 0) ? 1 : 0;
    }
    return cnt >= 7;
}

// async global -> LDS, 16B per lane; LDS dest is wave-uniform base (+lane*16B)
static __device__ __forceinline__ void gll16(const ushort* g, ushort* l) {
    __builtin_amdgcn_global_load_lds(
        (const __attribute__((address_space(1))) u32*)g,
        (__attribute__((address_space(3))) u32*)l, 16, 0, 0);
}

// -------------------------------------------------------------------------
// projkvpq: one 64x64 tile of K, V, P, AND Q from a single x staging pass.
// (unchanged from v11 — proven)
// -------------------------------------------------------------------------
__global__ __launch_bounds__(256) void projkvpq(
    const void* __restrict__ x,
    const void* __restrict__ Wk, const void* __restrict__ bk,
    const void* __restrict__ Wv, const void* __restrict__ bv,
    const void* __restrict__ Wp, const void* __restrict__ bp,
    const void* __restrict__ Wq, const void* __restrict__ bq,
    ushort* __restrict__ k_ws, ushort* __restrict__ v_ws,
    ushort* __restrict__ q_ws, float* __restrict__ out, int b0)
{
    __shared__ __align__(16) ushort A_lds[4][64 * 40];
    __shared__ __align__(16) ushort Bt_lds[64 * 40];
    __shared__ __align__(16) ushort T_lds[64 * 72];

    const bool isbf = detect_bf16(x);
    const int tid  = threadIdx.x;
    const int wave = tid >> 6;
    const int lane = tid & 63;
    const int l16  = lane & 15;
    const int quad = lane >> 4;

    const int n0 = blockIdx.x * 64;
    const int o0 = blockIdx.y * 64;
    const int bl = blockIdx.z;
    const int b  = b0 + bl;

    floatx4 zero4 = {0.f, 0.f, 0.f, 0.f};
    floatx4 acc[4][4];
    #pragma unroll
    for (int w = 0; w < 4; w++)
        #pragma unroll
        for (int t = 0; t < 4; t++) acc[w][t] = zero4;

    const void* Ws[4] = {Wk, Wv, Wp, Wq};

    for (int k0 = 0; k0 < CC; k0 += 32) {
        __syncthreads();
        {   // A[w] = W_w[o0..+64)[k0..+32)
            int row = tid >> 2, c8 = (tid & 3) * 8;
            #pragma unroll
            for (int w = 0; w < 4; w++)
                *(short8*)&A_lds[w][row * 40 + c8] =
                    load8(Ws[w], (size_t)(o0 + row) * CC + k0 + c8, isbf);
        }
        {   // Bt = x[k0..+32)[n0..+64) transposed -> [n][c]
            int c = tid >> 3, n8 = (tid & 7) * 8;
            short8 xv = load8(x, ((size_t)b * CC + k0 + c) * NN + n0 + n8, isbf);
            #pragma unroll
            for (int j = 0; j < 8; j++)
                Bt_lds[(n8 + j) * 40 + c] = ((ushort*)&xv)[j];
        }
        __syncthreads();

        short8 af[4];
        #pragma unroll
        for (int w = 0; w < 4; w++)
            af[w] = *(const short8*)&A_lds[w][(wave * 16 + l16) * 40 + quad * 8];
        #pragma unroll
        for (int t = 0; t < 4; t++) {
            short8 bf = *(const short8*)&Bt_lds[(t * 16 + l16) * 40 + quad * 8];
            #pragma unroll
            for (int w = 0; w < 4; w++)
                acc[w][t] = __builtin_amdgcn_mfma_f32_16x16x32_bf16(af[w], bf, acc[w][t], 0, 0, 0);
        }
    }

    float biasv[4][4];
    const void* Bs[4] = {bk, bv, bp, bq};
    #pragma unroll
    for (int w = 0; w < 4; w++)
        #pragma unroll
        for (int r = 0; r < 4; r++)
            biasv[w][r] = loadS(Bs[w], (size_t)(o0 + wave * 16 + quad * 4 + r), isbf);

    // ---- K epilogue: T[n][o], store [bl][n][C] ----
    __syncthreads();
    #pragma unroll
    for (int t = 0; t < 4; t++)
        #pragma unroll
        for (int r = 0; r < 4; r++)
            T_lds[(t * 16 + l16) * 72 + wave * 16 + quad * 4 + r] =
                f2bf(acc[0][t][r] + biasv[0][r]);
    __syncthreads();
    for (int u = tid; u < 512; u += 256) {
        int n = u >> 3, o8 = (u & 7) * 8;
        *(short8*)&k_ws[((size_t)bl * NN + n0 + n) * CC + o0 + o8] =
            *(const short8*)&T_lds[n * 72 + o8];
    }

    // ---- Q epilogue: T[n][o] scaled, store [bl][n][C] ----
    __syncthreads();
    #pragma unroll
    for (int t = 0; t < 4; t++)
        #pragma unroll
        for (int r = 0; r < 4; r++)
            T_lds[(t * 16 + l16) * 72 + wave * 16 + quad * 4 + r] =
                f2bf((acc[3][t][r] + biasv[3][r]) * 0.0625f);
    __syncthreads();
    for (int u = tid; u < 512; u += 256) {
        int n = u >> 3, o8 = (u & 7) * 8;
        *(short8*)&q_ws[((size_t)bl * NN + n0 + n) * CC + o0 + o8] =
            *(const short8*)&T_lds[n * 72 + o8];
    }

    // ---- V epilogue: T[o][n], store [bl][C][n] ----
    __syncthreads();
    #pragma unroll
    for (int t = 0; t < 4; t++)
        #pragma unroll
        for (int r = 0; r < 4; r++)
            T_lds[(wave * 16 + quad * 4 + r) * 72 + t * 16 + l16] =
                f2bf(acc[1][t][r] + biasv[1][r]);
    __syncthreads();
    for (int u = tid; u < 512; u += 256) {
        int o = u >> 3, n8 = (u & 7) * 8;
        *(short8*)&v_ws[((size_t)bl * CC + o0 + o) * NN + n0 + n8] =
            *(const short8*)&T_lds[o * 72 + n8];
    }

    // ---- P epilogue: direct fp32 stores ----
    #pragma unroll
    for (int t = 0; t < 4; t++)
        #pragma unroll
        for (int r = 0; r < 4; r++)
            out[((size_t)b * CC + o0 + wave * 16 + quad * 4 + r) * NN +
                n0 + t * 16 + l16] = acc[2][t][r] + biasv[2][r];
}

// -------------------------------------------------------------------------
// attn_mfma v12: v10 flash loop (V LDS-staged — v11's V-from-L2 reverted)
// + Q precomputed (no Phase A) + KV-split over blockIdx.z (cheap now) +
// __launch_bounds__(256,3): VGPR+AGPR <= 170 -> 3 blocks/CU, 12 waves/CU.
// grid (NN/64, BC, nsplit), block 256 (4 waves), LDS 37888 B.
// -------------------------------------------------------------------------
__global__ __launch_bounds__(256, 3) void attn_mfma(
    const ushort* __restrict__ q_ws, const ushort* __restrict__ k_ws,
    const ushort* __restrict__ v_ws, float* __restrict__ out,
    float* __restrict__ po, float* __restrict__ ml, int b0, int nsplit)
{
    // Pool: 18944 ushorts = 37888 B
    __shared__ __align__(16) ushort lds[18944];
    ushort* K_lds  = lds;            // [32][256] swizzled: slot p holds p^(row&7)
    ushort* Vt_lds = lds + 8192;     // [256][32] linear
    ushort* P_lds  = lds + 16384;    // [4][16][40] wave-local
    float*  Tf     = (float*)lds;    // [128][68] fp32 epilogue (aliases)

    const int tid  = threadIdx.x;
    const int wave = tid >> 6;
    const int lane = tid & 63;
    const int l16  = lane & 15;
    const int quad = lane >> 4;
    const int bl = blockIdx.y;
    const int b  = b0 + bl;
    const int n0 = blockIdx.x * 64;
    const int hs = blockIdx.z;

    floatx4 zero4 = {0.f, 0.f, 0.f, 0.f};

    // ---- load Q fragments (bf16, pre-scaled) straight from workspace ----
    const ushort* qp = q_ws + ((size_t)bl * NN + n0 + wave * 16 + l16) * CC;
    short8 qf[8];
    #pragma unroll
    for (int s = 0; s < 8; s++)
        qf[s] = *(const short8*)&qp[s * 32 + quad * 8];

    const ushort* kp = k_ws + (size_t)bl * NN * CC;   // [n][C]
    const ushort* vp = v_ws + (size_t)bl * CC * NN;   // [C][n]

    floatx4 Oacc[16];
    #pragma unroll
    for (int t = 0; t < 16; t++) Oacc[t] = zero4;
    // per-lane softmax state for q-row (wave*16 + l16); uniform across quad
    float mrow = -1e30f, lrow = 0.f;

    const int NT  = (NN / 32) / nsplit;
    const int it0 = hs * NT;

    #pragma unroll 1
    for (int it = it0; it < it0 + NT; ++it) {
        const int m0 = it * 32;
        __syncthreads();   // all waves done reading K/V/P of prev iter

        // stage K + V (16+16 1KB chunks, 8/wave), LDS dest linear,
        // K global source pre-swizzled (rule 21: source + read pair)
        #pragma unroll
        for (int i = 0; i < 4; i++) {
            int c = wave * 4 + i;
            {   // K chunk: 2 rows of 512 B; slot sw holds block sw^(row&7)
                int row = c * 2 + (lane >> 5);
                int sw  = (lane & 31) ^ (row & 7);
                gll16(kp + (size_t)(m0 + row) * CC + sw * 8, K_lds + c * 512);
            }
            {   // V chunk: 16 ch-rows of 64 B, linear
                int ch = c * 16 + (lane >> 2);
                gll16(vp + (size_t)ch * NN + m0 + (lane & 3) * 8, Vt_lds + c * 512);
            }
        }
        __syncthreads();   // vmcnt drained: tile visible (hidden by TLP)

        // QK^T SWAPPED: S[t] = mfma(K, Q): D[key][q-row], lane owns row l16
        floatx4 S[2];
        S[0] = zero4; S[1] = zero4;
        #pragma unroll
        for (int t = 0; t < 2; t++) {
            int row = t * 16 + l16;
            int rsw = row & 7;
            #pragma unroll
            for (int s = 0; s < 8; s++) {
                short8 kf = *(const short8*)&K_lds[row * 256 + ((s * 4 + quad) ^ rsw) * 8];
                S[t] = __builtin_amdgcn_mfma_f32_16x16x32_bf16(kf, qf[s], S[t], 0, 0, 0);
            }
        }

        // online softmax, per-lane row l16: in-lane reduce + 2 shuffles
        float mx = fmaxf(fmaxf(fmaxf(S[0][0], S[0][1]), fmaxf(S[0][2], S[0][3])),
                         fmaxf(fmaxf(S[1][0], S[1][1]), fmaxf(S[1][2], S[1][3])));
        mx = fmaxf(mx, __shfl_xor(mx, 16, 64));
        mx = fmaxf(mx, __shfl_xor(mx, 32, 64));

        if (__any(mx - mrow > 8.0f)) {   // defer-max (T13): rare after warmup
            float mn = fmaxf(mrow, mx);
            float al = __expf(mrow - mn);
            mrow = mn;
            lrow *= al;
            float a[4];
            #pragma unroll
            for (int r = 0; r < 4; r++) a[r] = __shfl(al, quad * 4 + r, 64);
            #pragma unroll
            for (int ct = 0; ct < 16; ct++)
                #pragma unroll
                for (int r = 0; r < 4; r++)
                    Oacc[ct][r] *= a[r];
        }

        // P = exp(S - m), pack to bf16, 2 x ds_write_b64 (wave-local rows)
        short4v w0, w1;
        float rs = 0.f;
        #pragma unroll
        for (int r = 0; r < 4; r++) {
            float p0 = __expf(S[0][r] - mrow);
            float p1 = __expf(S[1][r] - mrow);
            rs += p0 + p1;
            ((ushort*)&w0)[r] = f2bf(p0);
            ((ushort*)&w1)[r] = f2bf(p1);
        }
        rs += __shfl_xor(rs, 16, 64);
        rs += __shfl_xor(rs, 32, 64);
        lrow += rs;
        {   // P_lds[row l16][key]
            int base = wave * 640 + l16 * 40 + quad * 4;
            *(short4v*)&P_lds[base]      = w0;
            *(short4v*)&P_lds[base + 16] = w1;
        }

        // in-wave fence (DS in-order per wave); pin scheduler (rule 18)
        asm volatile("s_waitcnt lgkmcnt(0)" ::: "memory");
        __builtin_amdgcn_sched_barrier(0);

        // PV: O[ct] += P . V(16 ch of ct), one MFMA per ct (k=32)
        short8 pf = *(const short8*)&P_lds[wave * 640 + l16 * 40 + quad * 8];
        #pragma unroll
        for (int ct = 0; ct < 16; ct++) {
            int ch = ct * 16 + l16;
            short8 vf = *(const short8*)&Vt_lds[ch * 32 + quad * 8];
            Oacc[ct] = __builtin_amdgcn_mfma_f32_16x16x32_bf16(pf, vf, Oacc[ct], 0, 0, 0);
        }
    }

    if (nsplit == 1) {
        // ---- epilogue: out = h/l + P (fp32 RMW), two 128-channel halves ----
        float li = 1.0f / lrow;
        float linv[4];
        #pragma unroll
        for (int r = 0; r < 4; r++) linv[r] = __shfl(li, quad * 4 + r, 64);

        #pragma unroll
        for (int h = 0; h < 2; h++) {
            __syncthreads();
            #pragma unroll
            for (int ct = h * 8; ct < h * 8 + 8; ct++)
                #pragma unroll
                for (int r = 0; r < 4; r++)
                    Tf[(ct * 16 + l16 - h * 128) * 68 + wave * 16 + quad * 4 + r] =
                        Oacc[ct][r] * linv[r];
            __syncthreads();
            #pragma unroll
            for (int i = 0; i < 8; i++) {
                int u = tid + i * 256;
                int row = u >> 4, col4 = (u & 15) * 4;
                size_t gi = ((size_t)b * CC + h * 128 + row) * NN + n0 + col4;
                floatx4 pv = *(const floatx4*)&out[gi];
                floatx4 tv = *(const floatx4*)&Tf[row * 68 + col4];
                pv[0] += tv[0]; pv[1] += tv[1]; pv[2] += tv[2]; pv[3] += tv[3];
                *(floatx4*)&out[gi] = pv;
            }
        }
    } else {
        // ---- split epilogue: write unnormalized O + (m,l) partial ----
        const int pidx = (hs * NB + b) * (NN / 64) + blockIdx.x;
        float* pO = po + (size_t)pidx * (64 * 256);   // [ch][row]
        if (quad == 0) {   // mrow/lrow uniform across quad; row = wave*16+l16
            ml[(size_t)pidx * 128 + wave * 16 + l16]      = mrow;
            ml[(size_t)pidx * 128 + 64 + wave * 16 + l16] = lrow;
        }
        #pragma unroll
        for (int h = 0; h < 2; h++) {
            __syncthreads();
            #pragma unroll
            for (int ct = h * 8; ct < h * 8 + 8; ct++)
                #pragma unroll
                for (int r = 0; r < 4; r++)
                    Tf[(ct * 16 + l16 - h * 128) * 68 + wave * 16 + quad * 4 + r] =
                        Oacc[ct][r];
            __syncthreads();
            #pragma unroll
            for (int i = 0; i < 8; i++) {
                int u = tid + i * 256;
                int row = u >> 4, col4 = (u & 15) * 4;   // row = ch_local
                *(floatx4*)&pO[(size_t)(h * 128 + row) * 64 + col4] =
                    *(const floatx4*)&Tf[row * 68 + col4];
            }
        }
    }
}

// -------------------------------------------------------------------------
// attn_merge: combine the two split partials and RMW into out.
// (v9's kernel — verified correct in round 8)
// grid (NN/64, BC), block 256 (one thread per channel).
// -------------------------------------------------------------------------
__global__ __launch_bounds__(256) void attn_merge(
    const float* __restrict__ po, const float* __restrict__ ml,
    float* __restrict__ out, int b0)
{
    __shared__ float sm[4][64];   // m0,l0,m1,l1
    const int ntile = blockIdx.x;
    const int b = b0 + blockIdx.y;
    const int p0 = (0 * NB + b) * (NN / 64) + ntile;
    const int p1 = (1 * NB + b) * (NN / 64) + ntile;
    const float* O0 = po + (size_t)p0 * (64 * 256);
    const float* O1 = po + (size_t)p1 * (64 * 256);
    const int tid = threadIdx.x;
    if (tid < 64) {
        sm[0][tid] = ml[(size_t)p0 * 128 + tid];
        sm[1][tid] = ml[(size_t)p0 * 128 + 64 + tid];
    } else if (tid < 128) {
        int t = tid - 64;
        sm[2][t] = ml[(size_t)p1 * 128 + t];
        sm[3][t] = ml[(size_t)p1 * 128 + 64 + t];
    }
    __syncthreads();

    const int c = tid;
    float* op = out + ((size_t)b * CC + c) * NN + ntile * 64;
    const float* a = O0 + (size_t)c * 64;
    const float* d = O1 + (size_t)c * 64;
    #pragma unroll 4
    for (int r4 = 0; r4 < 64; r4 += 4) {
        floatx4 va = *(const floatx4*)&a[r4];
        floatx4 vd = *(const floatx4*)&d[r4];
        floatx4 vo = *(const floatx4*)&op[r4];
        #pragma unroll
        for (int j = 0; j < 4; j++) {
            int row = r4 + j;
            float m0 = sm[0][row], l0 = sm[1][row];
            float m1 = sm[2][row], l1 = sm[3][row];
            float M  = fmaxf(m0, m1);
            float w0 = __expf(m0 - M), w1 = __expf(m1 - M);
            float L  = l0 * w0 + l1 * w1;
            vo[j] += (va[j] * w0 + vd[j] * w1) / L;
        }
        *(floatx4*)&op[r4] = vo;
    }
}

// -------------------------------------------------------------------------
extern "C" void kernel_launch(void* const* d_in, const int* in_sizes, int n_in,
                              void* d_out, int out_size, void* d_ws, size_t ws_size,
                              hipStream_t stream) {
    int xi = 0;
    for (int i = 0; i < n_in; i++)
        if (in_sizes[i] == NB * CC * NN) xi = i;

    const void *x, *Wq, *bq, *Wk, *bk, *Wv, *bv, *Wp, *bp;
    if (xi == 0) {
        x  = d_in[0];
        Wq = d_in[1]; bq = d_in[2];
        Wk = d_in[3]; bk = d_in[4];
        Wv = d_in[5]; bv = d_in[6];
        Wp = d_in[7]; bp = d_in[8];
    } else {
        int wi[4], bi[4], nw = 0, nb = 0;
        for (int i = 0; i < n_in; i++) {
            if (i == xi) continue;
            if (in_sizes[i] == CC * CC) { if (nw < 4) wi[nw++] = i; }
            else                        { if (nb < 4) bi[nb++] = i; }
        }
        x  = d_in[xi];
        Wk = d_in[wi[0]]; Wp = d_in[wi[1]]; Wq = d_in[wi[2]]; Wv = d_in[wi[3]];
        bk = d_in[bi[0]]; bp = d_in[bi[1]]; bq = d_in[bi[2]]; bv = d_in[bi[3]];
    }

    float*  out = (float*)d_out;     // fp32 output
    ushort* ws  = (ushort*)d_ws;

    const size_t tsz_b = (size_t)NN * CC;
    int BC = 8;
    while (BC > 1 && (size_t)BC * tsz_b * 2 * 3 > ws_size) BC >>= 1;
    ushort* k_ws = ws;
    ushort* v_ws = ws + (size_t)BC * tsz_b;
    ushort* q_ws = ws + 2 * (size_t)BC * tsz_b;

    const size_t base_bytes = (size_t)3 * BC * tsz_b * 2;
    const size_t po_elems   = (size_t)2 * NB * (NN / 64) * 64 * 256;
    const size_t ml_elems   = (size_t)2 * NB * (NN / 64) * 128;
    const int nsplit = (BC == 8 &&
                        ws_size >= base_bytes + (po_elems + ml_elems) * 4) ? 2 : 1;
    float* po = (float*)(ws + 3 * (size_t)BC * tsz_b);
    float* ml = po + po_elems;

    for (int c0 = 0; c0 < NB; c0 += BC) {
        projkvpq<<<dim3(NN / 64, CC / 64, BC), dim3(256), 0, stream>>>(
            x, Wk, bk, Wv, bv, Wp, bp, Wq, bq, k_ws, v_ws, q_ws, out, c0);
        attn_mfma<<<dim3(NN / 64, BC, nsplit), dim3(256), 0, stream>>>(
            q_ws, k_ws, v_ws, out, po, ml, c0, nsplit);
        if (nsplit == 2)
            attn_merge<<<dim3(NN / 64, BC), dim3(256), 0, stream>>>(
                po, ml, out, c0);
    }
}

// Round 12
// 380.608 us; speedup vs baseline: 1.8267x; 1.2481x over previous
//
#include <hip/hip_runtime.h>

typedef __attribute__((ext_vector_type(8))) short short8;
typedef __attribute__((ext_vector_type(4))) short short4v;
typedef __attribute__((ext_vector_type(4))) float floatx4;
typedef unsigned int u32;

#define CC 256
#define NN 4096
#define NB 8

static __device__ __forceinline__ float b2f(ushort u) {
    union { unsigned int i; float f; } c;
    c.i = ((unsigned int)u) << 16;
    return c.f;
}

static __device__ __forceinline__ ushort f2bf(float f) {
    union { float f; unsigned int u; } c;
    c.f = f;
    unsigned int u = c.u;
    u += 0x7fffu + ((u >> 16) & 1u);
    return (ushort)(u >> 16);
}

static __device__ __forceinline__ short8 load8(const void* p, size_t idx, bool isbf) {
    if (isbf) {
        return *(const short8*)((const ushort*)p + idx);
    } else {
        const float* f = (const float*)p + idx;
        floatx4 a = *(const floatx4*)f;
        floatx4 b = *(const floatx4*)(f + 4);
        short8 r;
        #pragma unroll
        for (int j = 0; j < 4; j++) {
            ((ushort*)&r)[j]     = f2bf(a[j]);
            ((ushort*)&r)[j + 4] = f2bf(b[j]);
        }
        return r;
    }
}

static __device__ __forceinline__ float loadS(const void* p, size_t idx, bool isbf) {
    return isbf ? b2f(((const ushort*)p)[idx]) : ((const float*)p)[idx];
}

static __device__ __forceinline__ bool detect_bf16(const void* x) {
    const ushort* xu = (const ushort*)x;
    int cnt = 0;
    #pragma unroll
    for (int j = 0; j < 8; j++) {
        ushort u = xu[(size_t)j * 1048576];
        int e = (u >> 7) & 0xFF;
        cnt += ((e >= 100 && e <= 141) || (u & 0x7FFF) == 0) ? 1 : 0;
    }
    return cnt >= 7;
}

// async global -> LDS, 16B per lane; LDS dest is wave-uniform base (+lane*16B)
static __device__ __forceinline__ void gll16(const ushort* g, ushort* l) {
    __builtin_amdgcn_global_load_lds(
        (const __attribute__((address_space(1))) u32*)g,
        (__attribute__((address_space(3))) u32*)l, 16, 0, 0);
}

// -------------------------------------------------------------------------
// projkvpq: one 64x64 tile of K, V, P, AND Q from a single x staging pass.
// (unchanged from v11/v12 — proven)
// -------------------------------------------------------------------------
__global__ __launch_bounds__(256) void projkvpq(
    const void* __restrict__ x,
    const void* __restrict__ Wk, const void* __restrict__ bk,
    const void* __restrict__ Wv, const void* __restrict__ bv,
    const void* __restrict__ Wp, const void* __restrict__ bp,
    const void* __restrict__ Wq, const void* __restrict__ bq,
    ushort* __restrict__ k_ws, ushort* __restrict__ v_ws,
    ushort* __restrict__ q_ws, float* __restrict__ out, int b0)
{
    __shared__ __align__(16) ushort A_lds[4][64 * 40];
    __shared__ __align__(16) ushort Bt_lds[64 * 40];
    __shared__ __align__(16) ushort T_lds[64 * 72];

    const bool isbf = detect_bf16(x);
    const int tid  = threadIdx.x;
    const int wave = tid >> 6;
    const int lane = tid & 63;
    const int l16  = lane & 15;
    const int quad = lane >> 4;

    const int n0 = blockIdx.x * 64;
    const int o0 = blockIdx.y * 64;
    const int bl = blockIdx.z;
    const int b  = b0 + bl;

    floatx4 zero4 = {0.f, 0.f, 0.f, 0.f};
    floatx4 acc[4][4];
    #pragma unroll
    for (int w = 0; w < 4; w++)
        #pragma unroll
        for (int t = 0; t < 4; t++) acc[w][t] = zero4;

    const void* Ws[4] = {Wk, Wv, Wp, Wq};

    for (int k0 = 0; k0 < CC; k0 += 32) {
        __syncthreads();
        {   // A[w] = W_w[o0..+64)[k0..+32)
            int row = tid >> 2, c8 = (tid & 3) * 8;
            #pragma unroll
            for (int w = 0; w < 4; w++)
                *(short8*)&A_lds[w][row * 40 + c8] =
                    load8(Ws[w], (size_t)(o0 + row) * CC + k0 + c8, isbf);
        }
        {   // Bt = x[k0..+32)[n0..+64) transposed -> [n][c]
            int c = tid >> 3, n8 = (tid & 7) * 8;
            short8 xv = load8(x, ((size_t)b * CC + k0 + c) * NN + n0 + n8, isbf);
            #pragma unroll
            for (int j = 0; j < 8; j++)
                Bt_lds[(n8 + j) * 40 + c] = ((ushort*)&xv)[j];
        }
        __syncthreads();

        short8 af[4];
        #pragma unroll
        for (int w = 0; w < 4; w++)
            af[w] = *(const short8*)&A_lds[w][(wave * 16 + l16) * 40 + quad * 8];
        #pragma unroll
        for (int t = 0; t < 4; t++) {
            short8 bf = *(const short8*)&Bt_lds[(t * 16 + l16) * 40 + quad * 8];
            #pragma unroll
            for (int w = 0; w < 4; w++)
                acc[w][t] = __builtin_amdgcn_mfma_f32_16x16x32_bf16(af[w], bf, acc[w][t], 0, 0, 0);
        }
    }

    float biasv[4][4];
    const void* Bs[4] = {bk, bv, bp, bq};
    #pragma unroll
    for (int w = 0; w < 4; w++)
        #pragma unroll
        for (int r = 0; r < 4; r++)
            biasv[w][r] = loadS(Bs[w], (size_t)(o0 + wave * 16 + quad * 4 + r), isbf);

    // ---- K epilogue: T[n][o], store [bl][n][C] ----
    __syncthreads();
    #pragma unroll
    for (int t = 0; t < 4; t++)
        #pragma unroll
        for (int r = 0; r < 4; r++)
            T_lds[(t * 16 + l16) * 72 + wave * 16 + quad * 4 + r] =
                f2bf(acc[0][t][r] + biasv[0][r]);
    __syncthreads();
    for (int u = tid; u < 512; u += 256) {
        int n = u >> 3, o8 = (u & 7) * 8;
        *(short8*)&k_ws[((size_t)bl * NN + n0 + n) * CC + o0 + o8] =
            *(const short8*)&T_lds[n * 72 + o8];
    }

    // ---- Q epilogue: T[n][o] scaled, store [bl][n][C] ----
    __syncthreads();
    #pragma unroll
    for (int t = 0; t < 4; t++)
        #pragma unroll
        for (int r = 0; r < 4; r++)
            T_lds[(t * 16 + l16) * 72 + wave * 16 + quad * 4 + r] =
                f2bf((acc[3][t][r] + biasv[3][r]) * 0.0625f);
    __syncthreads();
    for (int u = tid; u < 512; u += 256) {
        int n = u >> 3, o8 = (u & 7) * 8;
        *(short8*)&q_ws[((size_t)bl * NN + n0 + n) * CC + o0 + o8] =
            *(const short8*)&T_lds[n * 72 + o8];
    }

    // ---- V epilogue: T[o][n], store [bl][C][n] ----
    __syncthreads();
    #pragma unroll
    for (int t = 0; t < 4; t++)
        #pragma unroll
        for (int r = 0; r < 4; r++)
            T_lds[(wave * 16 + quad * 4 + r) * 72 + t * 16 + l16] =
                f2bf(acc[1][t][r] + biasv[1][r]);
    __syncthreads();
    for (int u = tid; u < 512; u += 256) {
        int o = u >> 3, n8 = (u & 7) * 8;
        *(short8*)&v_ws[((size_t)bl * CC + o0 + o) * NN + n0 + n8] =
            *(const short8*)&T_lds[o * 72 + n8];
    }

    // ---- P epilogue: direct fp32 stores ----
    #pragma unroll
    for (int t = 0; t < 4; t++)
        #pragma unroll
        for (int r = 0; r < 4; r++)
            out[((size_t)b * CC + o0 + wave * 16 + quad * 4 + r) * NN +
                n0 + t * 16 + l16] = acc[2][t][r] + biasv[2][r];
}

// -------------------------------------------------------------------------
// attn_mfma v13: HK geometry. QBLK=256, 8 waves (512 thr), M=32 rows/wave
// (each kf/vf register fragment feeds 2 MFMAs), one 32KB K/V tile per CU,
// KV-split x2 -> 256 blocks = 1/CU. Per-CU LDS bytes per q-row ~2.4x lower
// than v10 (the measured bottleneck). Q precomputed; swapped QK^T; defer-max.
// grid (NN/256, BC, nsplit), block 512, LDS 67584 B.
// -------------------------------------------------------------------------
__global__ __launch_bounds__(512) void attn_mfma(
    const ushort* __restrict__ q_ws, const ushort* __restrict__ k_ws,
    const ushort* __restrict__ v_ws, float* __restrict__ out,
    float* __restrict__ po, float* __restrict__ ml, int b0, int nsplit)
{
    // Pool: 33792 ushorts = 67584 B (Tf epilogue is the high-water mark)
    __shared__ __align__(16) ushort lds[33792];
    ushort* K_lds  = lds;            // [32][256] swizzled: slot p holds p^(row&7)
    ushort* Vt_lds = lds + 8192;     // [256][32] linear
    ushort* P_lds  = lds + 16384;    // [8 waves][32 rows][40]
    float*  Tf     = (float*)lds;    // [64][264] fp32 epilogue chunk (aliases)

    const int tid  = threadIdx.x;
    const int wave = tid >> 6;       // 0..7
    const int lane = tid & 63;
    const int l16  = lane & 15;
    const int quad = lane >> 4;
    const int bl = blockIdx.y;
    const int b  = b0 + bl;
    const int n0 = blockIdx.x * 256;
    const int hs = blockIdx.z;

    floatx4 zero4 = {0.f, 0.f, 0.f, 0.f};

    // ---- load Q fragments for this wave's 32 rows (2 x 16-row halves) ----
    const ushort* qp = q_ws + ((size_t)bl * NN + n0 + wave * 32 + l16) * CC;
    short8 qf[2][8];
    #pragma unroll
    for (int f = 0; f < 2; f++)
        #pragma unroll
        for (int s = 0; s < 8; s++)
            qf[f][s] = *(const short8*)&qp[(size_t)(f * 16) * CC + s * 32 + quad * 8];

    const ushort* kp = k_ws + (size_t)bl * NN * CC;   // [n][C]
    const ushort* vp = v_ws + (size_t)bl * CC * NN;   // [C][n]

    floatx4 Oacc[2][16];
    #pragma unroll
    for (int f = 0; f < 2; f++)
        #pragma unroll
        for (int t = 0; t < 16; t++) Oacc[f][t] = zero4;
    float mrow[2] = {-1e30f, -1e30f}, lrow[2] = {0.f, 0.f};

    const int NT  = (NN / 32) / nsplit;
    const int it0 = hs * NT;

    #pragma unroll 1
    for (int it = it0; it < it0 + NT; ++it) {
        const int m0 = it * 32;
        __syncthreads();   // all waves done reading K/V/P of prev iter

        // stage K + V (16+16 1KB chunks, 4/wave), LDS dest linear,
        // K global source pre-swizzled (rule 21: source + read pair)
        #pragma unroll
        for (int i = 0; i < 2; i++) {
            int c = wave * 2 + i;    // 0..15
            {   // K chunk: 2 rows of 512 B; slot sw holds block sw^(row&7)
                int row = c * 2 + (lane >> 5);
                int sw  = (lane & 31) ^ (row & 7);
                gll16(kp + (size_t)(m0 + row) * CC + sw * 8, K_lds + c * 512);
            }
            {   // V chunk: 16 ch-rows of 64 B, linear
                int ch = c * 16 + (lane >> 2);
                gll16(vp + (size_t)ch * NN + m0 + (lane & 3) * 8, Vt_lds + c * 512);
            }
        }
        __syncthreads();   // vmcnt drained: tile visible

        // QK^T SWAPPED: S[f][t] = mfma(K, Q_f): D[key][q-row], kf shared
        floatx4 S[2][2];
        S[0][0] = zero4; S[0][1] = zero4; S[1][0] = zero4; S[1][1] = zero4;
        #pragma unroll
        for (int t = 0; t < 2; t++) {
            int row = t * 16 + l16;
            int rsw = row & 7;
            #pragma unroll
            for (int s = 0; s < 8; s++) {
                short8 kf = *(const short8*)&K_lds[row * 256 + ((s * 4 + quad) ^ rsw) * 8];
                S[0][t] = __builtin_amdgcn_mfma_f32_16x16x32_bf16(kf, qf[0][s], S[0][t], 0, 0, 0);
                S[1][t] = __builtin_amdgcn_mfma_f32_16x16x32_bf16(kf, qf[1][s], S[1][t], 0, 0, 0);
            }
        }

        // online softmax per f (lane owns q-rows wave*32 + f*16 + l16)
        float mx[2];
        #pragma unroll
        for (int f = 0; f < 2; f++) {
            float m = fmaxf(fmaxf(fmaxf(S[f][0][0], S[f][0][1]),
                                  fmaxf(S[f][0][2], S[f][0][3])),
                            fmaxf(fmaxf(S[f][1][0], S[f][1][1]),
                                  fmaxf(S[f][1][2], S[f][1][3])));
            m = fmaxf(m, __shfl_xor(m, 16, 64));
            m = fmaxf(m, __shfl_xor(m, 32, 64));
            mx[f] = m;
        }

        if (__any((mx[0] - mrow[0] > 8.0f) || (mx[1] - mrow[1] > 8.0f))) {
            float a[2][4];
            #pragma unroll
            for (int f = 0; f < 2; f++) {
                float mn = fmaxf(mrow[f], mx[f]);
                float al = __expf(mrow[f] - mn);
                mrow[f] = mn;
                lrow[f] *= al;
                #pragma unroll
                for (int r = 0; r < 4; r++) a[f][r] = __shfl(al, quad * 4 + r, 64);
            }
            #pragma unroll
            for (int f = 0; f < 2; f++)
                #pragma unroll
                for (int ct = 0; ct < 16; ct++)
                    #pragma unroll
                    for (int r = 0; r < 4; r++)
                        Oacc[f][ct][r] *= a[f][r];
        }

        // P = exp(S - m), pack bf16, 2 x ds_write_b64 per f (wave-local rows)
        #pragma unroll
        for (int f = 0; f < 2; f++) {
            short4v w0, w1;
            float rs = 0.f;
            #pragma unroll
            for (int r = 0; r < 4; r++) {
                float p0 = __expf(S[f][0][r] - mrow[f]);
                float p1 = __expf(S[f][1][r] - mrow[f]);
                rs += p0 + p1;
                ((ushort*)&w0)[r] = f2bf(p0);
                ((ushort*)&w1)[r] = f2bf(p1);
            }
            rs += __shfl_xor(rs, 16, 64);
            rs += __shfl_xor(rs, 32, 64);
            lrow[f] += rs;
            int base = wave * 1280 + (f * 16 + l16) * 40 + quad * 4;
            *(short4v*)&P_lds[base]      = w0;
            *(short4v*)&P_lds[base + 16] = w1;
        }

        // in-wave fence (DS in-order per wave); pin scheduler (rule 18)
        asm volatile("s_waitcnt lgkmcnt(0)" ::: "memory");
        __builtin_amdgcn_sched_barrier(0);

        // PV: O[f][ct] += P_f . V(16 ch of ct); vf shared across f
        short8 pf0 = *(const short8*)&P_lds[wave * 1280 + l16 * 40 + quad * 8];
        short8 pf1 = *(const short8*)&P_lds[wave * 1280 + (16 + l16) * 40 + quad * 8];
        #pragma unroll
        for (int ct = 0; ct < 16; ct++) {
            int ch = ct * 16 + l16;
            short8 vf = *(const short8*)&Vt_lds[ch * 32 + quad * 8];
            Oacc[0][ct] = __builtin_amdgcn_mfma_f32_16x16x32_bf16(pf0, vf, Oacc[0][ct], 0, 0, 0);
            Oacc[1][ct] = __builtin_amdgcn_mfma_f32_16x16x32_bf16(pf1, vf, Oacc[1][ct], 0, 0, 0);
        }
    }

    // ---- epilogue: 4 chunks of 64 channels through Tf [64][264] ----
    if (nsplit == 1) {
        float linv[2][4];
        #pragma unroll
        for (int f = 0; f < 2; f++) {
            float li = 1.0f / lrow[f];
            #pragma unroll
            for (int r = 0; r < 4; r++) linv[f][r] = __shfl(li, quad * 4 + r, 64);
        }
        #pragma unroll
        for (int c0 = 0; c0 < 4; c0++) {
            __syncthreads();
            #pragma unroll
            for (int j = 0; j < 4; j++) {
                int ct = c0 * 4 + j;
                #pragma unroll
                for (int f = 0; f < 2; f++)
                    #pragma unroll
                    for (int r = 0; r < 4; r++)
                        Tf[(j * 16 + l16) * 264 + wave * 32 + f * 16 + quad * 4 + r] =
                            Oacc[f][ct][r] * linv[f][r];
            }
            __syncthreads();
            #pragma unroll
            for (int i = 0; i < 8; i++) {
                int u = tid + i * 512;          // 4096 float4 slots = 64ch x 64
                int chl = u >> 6, col4 = (u & 63) * 4;
                size_t gi = ((size_t)b * CC + c0 * 64 + chl) * NN + n0 + col4;
                floatx4 pv = *(const floatx4*)&out[gi];
                floatx4 tv = *(const floatx4*)&Tf[chl * 264 + col4];
                pv[0] += tv[0]; pv[1] += tv[1]; pv[2] += tv[2]; pv[3] += tv[3];
                *(floatx4*)&out[gi] = pv;
            }
        }
    } else {
        const int pidx = (hs * NB + b) * (NN / 256) + blockIdx.x;
        float* pO = po + (size_t)pidx * (256 * 256);   // [ch][row]
        if (quad == 0) {
            #pragma unroll
            for (int f = 0; f < 2; f++) {
                int row = wave * 32 + f * 16 + l16;
                ml[(size_t)pidx * 512 + row]       = mrow[f];
                ml[(size_t)pidx * 512 + 256 + row] = lrow[f];
            }
        }
        #pragma unroll
        for (int c0 = 0; c0 < 4; c0++) {
            __syncthreads();
            #pragma unroll
            for (int j = 0; j < 4; j++) {
                int ct = c0 * 4 + j;
                #pragma unroll
                for (int f = 0; f < 2; f++)
                    #pragma unroll
                    for (int r = 0; r < 4; r++)
                        Tf[(j * 16 + l16) * 264 + wave * 32 + f * 16 + quad * 4 + r] =
                            Oacc[f][ct][r];
            }
            __syncthreads();
            #pragma unroll
            for (int i = 0; i < 8; i++) {
                int u = tid + i * 512;
                int chl = u >> 6, col4 = (u & 63) * 4;
                *(floatx4*)&pO[(size_t)(c0 * 64 + chl) * 256 + col4] =
                    *(const floatx4*)&Tf[chl * 264 + col4];
            }
        }
    }
}

// -------------------------------------------------------------------------
// attn_merge: combine the two split partials and RMW into out.
// grid (NN/256, BC), block 256 (one thread per channel, 256-row tiles).
// -------------------------------------------------------------------------
__global__ __launch_bounds__(256) void attn_merge(
    const float* __restrict__ po, const float* __restrict__ ml,
    float* __restrict__ out, int b0)
{
    __shared__ float sm[4][256];   // m0,l0,m1,l1 per q-row
    const int ntile = blockIdx.x;
    const int b = b0 + blockIdx.y;
    const int NT2 = NN / 256;
    const int p0 = (0 * NB + b) * NT2 + ntile;
    const int p1 = (1 * NB + b) * NT2 + ntile;
    const float* O0 = po + (size_t)p0 * (256 * 256);
    const float* O1 = po + (size_t)p1 * (256 * 256);
    const int tid = threadIdx.x;
    sm[0][tid] = ml[(size_t)p0 * 512 + tid];
    sm[1][tid] = ml[(size_t)p0 * 512 + 256 + tid];
    sm[2][tid] = ml[(size_t)p1 * 512 + tid];
    sm[3][tid] = ml[(size_t)p1 * 512 + 256 + tid];
    __syncthreads();

    const int c = tid;
    float* op = out + ((size_t)b * CC + c) * NN + ntile * 256;
    const float* a = O0 + (size_t)c * 256;
    const float* d = O1 + (size_t)c * 256;
    #pragma unroll 4
    for (int r4 = 0; r4 < 256; r4 += 4) {
        floatx4 va = *(const floatx4*)&a[r4];
        floatx4 vd = *(const floatx4*)&d[r4];
        floatx4 vo = *(const floatx4*)&op[r4];
        #pragma unroll
        for (int j = 0; j < 4; j++) {
            int row = r4 + j;
            float m0 = sm[0][row], l0 = sm[1][row];
            float m1 = sm[2][row], l1 = sm[3][row];
            float M  = fmaxf(m0, m1);
            float w0 = __expf(m0 - M), w1 = __expf(m1 - M);
            float L  = l0 * w0 + l1 * w1;
            vo[j] += (va[j] * w0 + vd[j] * w1) / L;
        }
        *(floatx4*)&op[r4] = vo;
    }
}

// -------------------------------------------------------------------------
extern "C" void kernel_launch(void* const* d_in, const int* in_sizes, int n_in,
                              void* d_out, int out_size, void* d_ws, size_t ws_size,
                              hipStream_t stream) {
    int xi = 0;
    for (int i = 0; i < n_in; i++)
        if (in_sizes[i] == NB * CC * NN) xi = i;

    const void *x, *Wq, *bq, *Wk, *bk, *Wv, *bv, *Wp, *bp;
    if (xi == 0) {
        x  = d_in[0];
        Wq = d_in[1]; bq = d_in[2];
        Wk = d_in[3]; bk = d_in[4];
        Wv = d_in[5]; bv = d_in[6];
        Wp = d_in[7]; bp = d_in[8];
    } else {
        int wi[4], bi[4], nw = 0, nb = 0;
        for (int i = 0; i < n_in; i++) {
            if (i == xi) continue;
            if (in_sizes[i] == CC * CC) { if (nw < 4) wi[nw++] = i; }
            else                        { if (nb < 4) bi[nb++] = i; }
        }
        x  = d_in[xi];
        Wk = d_in[wi[0]]; Wp = d_in[wi[1]]; Wq = d_in[wi[2]]; Wv = d_in[wi[3]];
        bk = d_in[bi[0]]; bp = d_in[bi[1]]; bq = d_in[bi[2]]; bv = d_in[bi[3]];
    }

    float*  out = (float*)d_out;     // fp32 output
    ushort* ws  = (ushort*)d_ws;

    const size_t tsz_b = (size_t)NN * CC;
    int BC = 8;
    while (BC > 1 && (size_t)BC * tsz_b * 2 * 3 > ws_size) BC >>= 1;
    ushort* k_ws = ws;
    ushort* v_ws = ws + (size_t)BC * tsz_b;
    ushort* q_ws = ws + 2 * (size_t)BC * tsz_b;

    const size_t base_bytes = (size_t)3 * BC * tsz_b * 2;
    const size_t po_elems   = (size_t)2 * NB * (NN / 256) * 256 * 256;
    const size_t ml_elems   = (size_t)2 * NB * (NN / 256) * 512;
    const int nsplit = (BC == 8 &&
                        ws_size >= base_bytes + (po_elems + ml_elems) * 4) ? 2 : 1;
    float* po = (float*)(ws + 3 * (size_t)BC * tsz_b);
    float* ml = po + po_elems;

    for (int c0 = 0; c0 < NB; c0 += BC) {
        projkvpq<<<dim3(NN / 64, CC / 64, BC), dim3(256), 0, stream>>>(
            x, Wk, bk, Wv, bv, Wp, bp, Wq, bq, k_ws, v_ws, q_ws, out, c0);
        attn_mfma<<<dim3(NN / 256, BC, nsplit), dim3(512), 0, stream>>>(
            q_ws, k_ws, v_ws, out, po, ml, c0, nsplit);
        if (nsplit == 2)
            attn_merge<<<dim3(NN / 256, BC), dim3(256), 0, stream>>>(
                po, ml, out, c0);
    }
}

// Round 13
// 356.360 us; speedup vs baseline: 1.9510x; 1.0680x over previous
//
#include <hip/hip_runtime.h>

typedef __attribute__((ext_vector_type(8))) short short8;
typedef __attribute__((ext_vector_type(4))) short short4v;
typedef __attribute__((ext_vector_type(4))) float floatx4;
typedef unsigned int u32;

#define CC 256
#define NN 4096
#define NB 8

static __device__ __forceinline__ float b2f(ushort u) {
    union { unsigned int i; float f; } c;
    c.i = ((unsigned int)u) << 16;
    return c.f;
}

static __device__ __forceinline__ ushort f2bf(float f) {
    union { float f; unsigned int u; } c;
    c.f = f;
    unsigned int u = c.u;
    u += 0x7fffu + ((u >> 16) & 1u);
    return (ushort)(u >> 16);
}

static __device__ __forceinline__ short8 load8(const void* p, size_t idx, bool isbf) {
    if (isbf) {
        return *(const short8*)((const ushort*)p + idx);
    } else {
        const float* f = (const float*)p + idx;
        floatx4 a = *(const floatx4*)f;
        floatx4 b = *(const floatx4*)(f + 4);
        short8 r;
        #pragma unroll
        for (int j = 0; j < 4; j++) {
            ((ushort*)&r)[j]     = f2bf(a[j]);
            ((ushort*)&r)[j + 4] = f2bf(b[j]);
        }
        return r;
    }
}

static __device__ __forceinline__ float loadS(const void* p, size_t idx, bool isbf) {
    return isbf ? b2f(((const ushort*)p)[idx]) : ((const float*)p)[idx];
}

static __device__ __forceinline__ bool detect_bf16(const void* x) {
    const ushort* xu = (const ushort*)x;
    int cnt = 0;
    #pragma unroll
    for (int j = 0; j < 8; j++) {
        ushort u = xu[(size_t)j * 1048576];
        int e = (u >> 7) & 0xFF;
        cnt += ((e >= 100 && e <= 141) || (u & 0x7FFF) == 0) ? 1 : 0;
    }
    return cnt >= 7;
}

// async global -> LDS, 16B per lane; LDS dest is wave-uniform base (+lane*16B)
static __device__ __forceinline__ void gll16(const ushort* g, ushort* l) {
    __builtin_amdgcn_global_load_lds(
        (const __attribute__((address_space(1))) u32*)g,
        (__attribute__((address_space(3))) u32*)l, 16, 0, 0);
}

// -------------------------------------------------------------------------
// projkvpq: one 64x64 tile of K, V, P, AND Q from a single x staging pass.
// (unchanged — proven)
// -------------------------------------------------------------------------
__global__ __launch_bounds__(256) void projkvpq(
    const void* __restrict__ x,
    const void* __restrict__ Wk, const void* __restrict__ bk,
    const void* __restrict__ Wv, const void* __restrict__ bv,
    const void* __restrict__ Wp, const void* __restrict__ bp,
    const void* __restrict__ Wq, const void* __restrict__ bq,
    ushort* __restrict__ k_ws, ushort* __restrict__ v_ws,
    ushort* __restrict__ q_ws, float* __restrict__ out, int b0)
{
    __shared__ __align__(16) ushort A_lds[4][64 * 40];
    __shared__ __align__(16) ushort Bt_lds[64 * 40];
    __shared__ __align__(16) ushort T_lds[64 * 72];

    const bool isbf = detect_bf16(x);
    const int tid  = threadIdx.x;
    const int wave = tid >> 6;
    const int lane = tid & 63;
    const int l16  = lane & 15;
    const int quad = lane >> 4;

    const int n0 = blockIdx.x * 64;
    const int o0 = blockIdx.y * 64;
    const int bl = blockIdx.z;
    const int b  = b0 + bl;

    floatx4 zero4 = {0.f, 0.f, 0.f, 0.f};
    floatx4 acc[4][4];
    #pragma unroll
    for (int w = 0; w < 4; w++)
        #pragma unroll
        for (int t = 0; t < 4; t++) acc[w][t] = zero4;

    const void* Ws[4] = {Wk, Wv, Wp, Wq};

    for (int k0 = 0; k0 < CC; k0 += 32) {
        __syncthreads();
        {   // A[w] = W_w[o0..+64)[k0..+32)
            int row = tid >> 2, c8 = (tid & 3) * 8;
            #pragma unroll
            for (int w = 0; w < 4; w++)
                *(short8*)&A_lds[w][row * 40 + c8] =
                    load8(Ws[w], (size_t)(o0 + row) * CC + k0 + c8, isbf);
        }
        {   // Bt = x[k0..+32)[n0..+64) transposed -> [n][c]
            int c = tid >> 3, n8 = (tid & 7) * 8;
            short8 xv = load8(x, ((size_t)b * CC + k0 + c) * NN + n0 + n8, isbf);
            #pragma unroll
            for (int j = 0; j < 8; j++)
                Bt_lds[(n8 + j) * 40 + c] = ((ushort*)&xv)[j];
        }
        __syncthreads();

        short8 af[4];
        #pragma unroll
        for (int w = 0; w < 4; w++)
            af[w] = *(const short8*)&A_lds[w][(wave * 16 + l16) * 40 + quad * 8];
        #pragma unroll
        for (int t = 0; t < 4; t++) {
            short8 bf = *(const short8*)&Bt_lds[(t * 16 + l16) * 40 + quad * 8];
            #pragma unroll
            for (int w = 0; w < 4; w++)
                acc[w][t] = __builtin_amdgcn_mfma_f32_16x16x32_bf16(af[w], bf, acc[w][t], 0, 0, 0);
        }
    }

    float biasv[4][4];
    const void* Bs[4] = {bk, bv, bp, bq};
    #pragma unroll
    for (int w = 0; w < 4; w++)
        #pragma unroll
        for (int r = 0; r < 4; r++)
            biasv[w][r] = loadS(Bs[w], (size_t)(o0 + wave * 16 + quad * 4 + r), isbf);

    // ---- K epilogue: T[n][o], store [bl][n][C] ----
    __syncthreads();
    #pragma unroll
    for (int t = 0; t < 4; t++)
        #pragma unroll
        for (int r = 0; r < 4; r++)
            T_lds[(t * 16 + l16) * 72 + wave * 16 + quad * 4 + r] =
                f2bf(acc[0][t][r] + biasv[0][r]);
    __syncthreads();
    for (int u = tid; u < 512; u += 256) {
        int n = u >> 3, o8 = (u & 7) * 8;
        *(short8*)&k_ws[((size_t)bl * NN + n0 + n) * CC + o0 + o8] =
            *(const short8*)&T_lds[n * 72 + o8];
    }

    // ---- Q epilogue: T[n][o] scaled, store [bl][n][C] ----
    __syncthreads();
    #pragma unroll
    for (int t = 0; t < 4; t++)
        #pragma unroll
        for (int r = 0; r < 4; r++)
            T_lds[(t * 16 + l16) * 72 + wave * 16 + quad * 4 + r] =
                f2bf((acc[3][t][r] + biasv[3][r]) * 0.0625f);
    __syncthreads();
    for (int u = tid; u < 512; u += 256) {
        int n = u >> 3, o8 = (u & 7) * 8;
        *(short8*)&q_ws[((size_t)bl * NN + n0 + n) * CC + o0 + o8] =
            *(const short8*)&T_lds[n * 72 + o8];
    }

    // ---- V epilogue: T[o][n], store [bl][C][n] ----
    __syncthreads();
    #pragma unroll
    for (int t = 0; t < 4; t++)
        #pragma unroll
        for (int r = 0; r < 4; r++)
            T_lds[(wave * 16 + quad * 4 + r) * 72 + t * 16 + l16] =
                f2bf(acc[1][t][r] + biasv[1][r]);
    __syncthreads();
    for (int u = tid; u < 512; u += 256) {
        int o = u >> 3, n8 = (u & 7) * 8;
        *(short8*)&v_ws[((size_t)bl * CC + o0 + o) * NN + n0 + n8] =
            *(const short8*)&T_lds[o * 72 + n8];
    }

    // ---- P epilogue: direct fp32 stores ----
    #pragma unroll
    for (int t = 0; t < 4; t++)
        #pragma unroll
        for (int r = 0; r < 4; r++)
            out[((size_t)b * CC + o0 + wave * 16 + quad * 4 + r) * NN +
                n0 + t * 16 + l16] = acc[2][t][r] + biasv[2][r];
}

// -------------------------------------------------------------------------
// attn_mfma v14 = v13 (QBLK=256, 8 waves, M=32/wave — proven 198us) +
// double-buffered K/V staging with counted vmcnt (never 0 in loop) and raw
// s_barrier: stage(it+1) issued each iter, wait vmcnt(4) = tile it landed.
// At 1 block/CU nothing else hides the drain — this is the regime where
// the v7 mechanism pays. LDS 86016 B. grid (NN/256, BC, nsplit), block 512.
// -------------------------------------------------------------------------
__global__ __launch_bounds__(512) void attn_mfma(
    const ushort* __restrict__ q_ws, const ushort* __restrict__ k_ws,
    const ushort* __restrict__ v_ws, float* __restrict__ out,
    float* __restrict__ po, float* __restrict__ ml, int b0, int nsplit)
{
    // Pool: 43008 ushorts = 86016 B (K dbuf 2x16KB, V dbuf 2x16KB, P 20KB)
    __shared__ __align__(16) ushort lds[43008];
    ushort* K0_lds = lds;            // [32][256] swizzled
    ushort* K1_lds = lds + 8192;
    ushort* V0_lds = lds + 16384;    // [256][32] linear
    ushort* V1_lds = lds + 24576;
    ushort* P_lds  = lds + 32768;    // [8 waves][32 rows][40]
    float*  Tf     = (float*)lds;    // [64][264] fp32 epilogue chunk (aliases)

    const int tid  = threadIdx.x;
    const int wave = tid >> 6;       // 0..7
    const int lane = tid & 63;
    const int l16  = lane & 15;
    const int quad = lane >> 4;
    const int bl = blockIdx.y;
    const int b  = b0 + bl;
    const int n0 = blockIdx.x * 256;
    const int hs = blockIdx.z;

    floatx4 zero4 = {0.f, 0.f, 0.f, 0.f};

    // ---- load Q fragments for this wave's 32 rows (2 x 16-row halves) ----
    const ushort* qp = q_ws + ((size_t)bl * NN + n0 + wave * 32 + l16) * CC;
    short8 qf[2][8];
    #pragma unroll
    for (int f = 0; f < 2; f++)
        #pragma unroll
        for (int s = 0; s < 8; s++)
            qf[f][s] = *(const short8*)&qp[(size_t)(f * 16) * CC + s * 32 + quad * 8];

    const ushort* kp = k_ws + (size_t)bl * NN * CC;   // [n][C]
    const ushort* vp = v_ws + (size_t)bl * CC * NN;   // [C][n]

    floatx4 Oacc[2][16];
    #pragma unroll
    for (int f = 0; f < 2; f++)
        #pragma unroll
        for (int t = 0; t < 16; t++) Oacc[f][t] = zero4;
    float mrow[2] = {-1e30f, -1e30f}, lrow[2] = {0.f, 0.f};

    const int NT  = (NN / 32) / nsplit;
    const int it0 = hs * NT;
    const int itE = it0 + NT;

    // stage one 32-key tile (4 gll16/wave: 2 K-chunks + 2 V-chunks)
    auto stage = [&](int it, ushort* kb, ushort* vb) {
        int m0 = it * 32;
        #pragma unroll
        for (int i = 0; i < 2; i++) {
            int c = wave * 2 + i;    // 0..15
            {   // K chunk: 2 rows of 512 B; slot sw holds block sw^(row&7)
                int row = c * 2 + (lane >> 5);
                int sw  = (lane & 31) ^ (row & 7);
                gll16(kp + (size_t)(m0 + row) * CC + sw * 8, kb + c * 512);
            }
            {   // V chunk: 16 ch-rows of 64 B, linear
                int ch = c * 16 + (lane >> 2);
                gll16(vp + (size_t)ch * NN + m0 + (lane & 3) * 8, vb + c * 512);
            }
        }
    };

    stage(it0, K0_lds, V0_lds);   // prologue: 4 loads in flight

    #pragma unroll 1
    for (int it = it0; it < itE; ++it) {
        const int cb = (it - it0) & 1;
        ushort* Kc = cb ? K1_lds : K0_lds;
        ushort* Vc = cb ? V1_lds : V0_lds;

        if (it + 1 < itE) {
            stage(it + 1, cb ? K0_lds : K1_lds, cb ? V0_lds : V1_lds);
            asm volatile("s_waitcnt vmcnt(4)" ::: "memory");   // tile it landed
        } else {
            asm volatile("s_waitcnt vmcnt(0)" ::: "memory");
        }
        __builtin_amdgcn_s_barrier();   // tile it visible block-wide

        // QK^T SWAPPED: S[f][t] = mfma(K, Q_f): D[key][q-row], kf shared
        floatx4 S[2][2];
        S[0][0] = zero4; S[0][1] = zero4; S[1][0] = zero4; S[1][1] = zero4;
        #pragma unroll
        for (int t = 0; t < 2; t++) {
            int row = t * 16 + l16;
            int rsw = row & 7;
            #pragma unroll
            for (int s = 0; s < 8; s++) {
                short8 kf = *(const short8*)&Kc[row * 256 + ((s * 4 + quad) ^ rsw) * 8];
                S[0][t] = __builtin_amdgcn_mfma_f32_16x16x32_bf16(kf, qf[0][s], S[0][t], 0, 0, 0);
                S[1][t] = __builtin_amdgcn_mfma_f32_16x16x32_bf16(kf, qf[1][s], S[1][t], 0, 0, 0);
            }
        }

        // online softmax per f (lane owns q-rows wave*32 + f*16 + l16)
        float mx[2];
        #pragma unroll
        for (int f = 0; f < 2; f++) {
            float m = fmaxf(fmaxf(fmaxf(S[f][0][0], S[f][0][1]),
                                  fmaxf(S[f][0][2], S[f][0][3])),
                            fmaxf(fmaxf(S[f][1][0], S[f][1][1]),
                                  fmaxf(S[f][1][2], S[f][1][3])));
            m = fmaxf(m, __shfl_xor(m, 16, 64));
            m = fmaxf(m, __shfl_xor(m, 32, 64));
            mx[f] = m;
        }

        if (__any((mx[0] - mrow[0] > 8.0f) || (mx[1] - mrow[1] > 8.0f))) {
            float a[2][4];
            #pragma unroll
            for (int f = 0; f < 2; f++) {
                float mn = fmaxf(mrow[f], mx[f]);
                float al = __expf(mrow[f] - mn);
                mrow[f] = mn;
                lrow[f] *= al;
                #pragma unroll
                for (int r = 0; r < 4; r++) a[f][r] = __shfl(al, quad * 4 + r, 64);
            }
            #pragma unroll
            for (int f = 0; f < 2; f++)
                #pragma unroll
                for (int ct = 0; ct < 16; ct++)
                    #pragma unroll
                    for (int r = 0; r < 4; r++)
                        Oacc[f][ct][r] *= a[f][r];
        }

        // P = exp(S - m), pack bf16, 2 x ds_write_b64 per f (wave-local rows)
        #pragma unroll
        for (int f = 0; f < 2; f++) {
            short4v w0, w1;
            float rs = 0.f;
            #pragma unroll
            for (int r = 0; r < 4; r++) {
                float p0 = __expf(S[f][0][r] - mrow[f]);
                float p1 = __expf(S[f][1][r] - mrow[f]);
                rs += p0 + p1;
                ((ushort*)&w0)[r] = f2bf(p0);
                ((ushort*)&w1)[r] = f2bf(p1);
            }
            rs += __shfl_xor(rs, 16, 64);
            rs += __shfl_xor(rs, 32, 64);
            lrow[f] += rs;
            int base = wave * 1280 + (f * 16 + l16) * 40 + quad * 4;
            *(short4v*)&P_lds[base]      = w0;
            *(short4v*)&P_lds[base + 16] = w1;
        }

        // in-wave fence (DS in-order per wave); pin scheduler (rule 18)
        asm volatile("s_waitcnt lgkmcnt(0)" ::: "memory");
        __builtin_amdgcn_sched_barrier(0);

        // PV: O[f][ct] += P_f . V(16 ch of ct); vf shared across f
        short8 pf0 = *(const short8*)&P_lds[wave * 1280 + l16 * 40 + quad * 8];
        short8 pf1 = *(const short8*)&P_lds[wave * 1280 + (16 + l16) * 40 + quad * 8];
        #pragma unroll
        for (int ct = 0; ct < 16; ct++) {
            int ch = ct * 16 + l16;
            short8 vf = *(const short8*)&Vc[ch * 32 + quad * 8];
            Oacc[0][ct] = __builtin_amdgcn_mfma_f32_16x16x32_bf16(pf0, vf, Oacc[0][ct], 0, 0, 0);
            Oacc[1][ct] = __builtin_amdgcn_mfma_f32_16x16x32_bf16(pf1, vf, Oacc[1][ct], 0, 0, 0);
        }

        // all ds reads of buf cb retired -> barrier -> it+2 may stage into cb
        asm volatile("s_waitcnt lgkmcnt(0)" ::: "memory");
        __builtin_amdgcn_sched_barrier(0);
        __builtin_amdgcn_s_barrier();
    }

    // ---- epilogue: 4 chunks of 64 channels through Tf [64][264] ----
    if (nsplit == 1) {
        float linv[2][4];
        #pragma unroll
        for (int f = 0; f < 2; f++) {
            float li = 1.0f / lrow[f];
            #pragma unroll
            for (int r = 0; r < 4; r++) linv[f][r] = __shfl(li, quad * 4 + r, 64);
        }
        #pragma unroll
        for (int c0 = 0; c0 < 4; c0++) {
            __syncthreads();
            #pragma unroll
            for (int j = 0; j < 4; j++) {
                int ct = c0 * 4 + j;
                #pragma unroll
                for (int f = 0; f < 2; f++)
                    #pragma unroll
                    for (int r = 0; r < 4; r++)
                        Tf[(j * 16 + l16) * 264 + wave * 32 + f * 16 + quad * 4 + r] =
                            Oacc[f][ct][r] * linv[f][r];
            }
            __syncthreads();
            #pragma unroll
            for (int i = 0; i < 8; i++) {
                int u = tid + i * 512;          // 4096 float4 slots = 64ch x 64
                int chl = u >> 6, col4 = (u & 63) * 4;
                size_t gi = ((size_t)b * CC + c0 * 64 + chl) * NN + n0 + col4;
                floatx4 pv = *(const floatx4*)&out[gi];
                floatx4 tv = *(const floatx4*)&Tf[chl * 264 + col4];
                pv[0] += tv[0]; pv[1] += tv[1]; pv[2] += tv[2]; pv[3] += tv[3];
                *(floatx4*)&out[gi] = pv;
            }
        }
    } else {
        const int pidx = (hs * NB + b) * (NN / 256) + blockIdx.x;
        float* pO = po + (size_t)pidx * (256 * 256);   // [ch][row]
        if (quad == 0) {
            #pragma unroll
            for (int f = 0; f < 2; f++) {
                int row = wave * 32 + f * 16 + l16;
                ml[(size_t)pidx * 512 + row]       = mrow[f];
                ml[(size_t)pidx * 512 + 256 + row] = lrow[f];
            }
        }
        #pragma unroll
        for (int c0 = 0; c0 < 4; c0++) {
            __syncthreads();
            #pragma unroll
            for (int j = 0; j < 4; j++) {
                int ct = c0 * 4 + j;
                #pragma unroll
                for (int f = 0; f < 2; f++)
                    #pragma unroll
                    for (int r = 0; r < 4; r++)
                        Tf[(j * 16 + l16) * 264 + wave * 32 + f * 16 + quad * 4 + r] =
                            Oacc[f][ct][r];
            }
            __syncthreads();
            #pragma unroll
            for (int i = 0; i < 8; i++) {
                int u = tid + i * 512;
                int chl = u >> 6, col4 = (u & 63) * 4;
                *(floatx4*)&pO[(size_t)(c0 * 64 + chl) * 256 + col4] =
                    *(const floatx4*)&Tf[chl * 264 + col4];
            }
        }
    }
}

// -------------------------------------------------------------------------
// attn_merge: combine the two split partials and RMW into out.
// grid (NN/256, BC), block 256 (one thread per channel, 256-row tiles).
// -------------------------------------------------------------------------
__global__ __launch_bounds__(256) void attn_merge(
    const float* __restrict__ po, const float* __restrict__ ml,
    float* __restrict__ out, int b0)
{
    __shared__ float sm[4][256];   // m0,l0,m1,l1 per q-row
    const int ntile = blockIdx.x;
    const int b = b0 + blockIdx.y;
    const int NT2 = NN / 256;
    const int p0 = (0 * NB + b) * NT2 + ntile;
    const int p1 = (1 * NB + b) * NT2 + ntile;
    const float* O0 = po + (size_t)p0 * (256 * 256);
    const float* O1 = po + (size_t)p1 * (256 * 256);
    const int tid = threadIdx.x;
    sm[0][tid] = ml[(size_t)p0 * 512 + tid];
    sm[1][tid] = ml[(size_t)p0 * 512 + 256 + tid];
    sm[2][tid] = ml[(size_t)p1 * 512 + tid];
    sm[3][tid] = ml[(size_t)p1 * 512 + 256 + tid];
    __syncthreads();

    const int c = tid;
    float* op = out + ((size_t)b * CC + c) * NN + ntile * 256;
    const float* a = O0 + (size_t)c * 256;
    const float* d = O1 + (size_t)c * 256;
    #pragma unroll 4
    for (int r4 = 0; r4 < 256; r4 += 4) {
        floatx4 va = *(const floatx4*)&a[r4];
        floatx4 vd = *(const floatx4*)&d[r4];
        floatx4 vo = *(const floatx4*)&op[r4];
        #pragma unroll
        for (int j = 0; j < 4; j++) {
            int row = r4 + j;
            float m0 = sm[0][row], l0 = sm[1][row];
            float m1 = sm[2][row], l1 = sm[3][row];
            float M  = fmaxf(m0, m1);
            float w0 = __expf(m0 - M), w1 = __expf(m1 - M);
            float L  = l0 * w0 + l1 * w1;
            vo[j] += (va[j] * w0 + vd[j] * w1) / L;
        }
        *(floatx4*)&op[r4] = vo;
    }
}

// -------------------------------------------------------------------------
extern "C" void kernel_launch(void* const* d_in, const int* in_sizes, int n_in,
                              void* d_out, int out_size, void* d_ws, size_t ws_size,
                              hipStream_t stream) {
    int xi = 0;
    for (int i = 0; i < n_in; i++)
        if (in_sizes[i] == NB * CC * NN) xi = i;

    const void *x, *Wq, *bq, *Wk, *bk, *Wv, *bv, *Wp, *bp;
    if (xi == 0) {
        x  = d_in[0];
        Wq = d_in[1]; bq = d_in[2];
        Wk = d_in[3]; bk = d_in[4];
        Wv = d_in[5]; bv = d_in[6];
        Wp = d_in[7]; bp = d_in[8];
    } else {
        int wi[4], bi[4], nw = 0, nb = 0;
        for (int i = 0; i < n_in; i++) {
            if (i == xi) continue;
            if (in_sizes[i] == CC * CC) { if (nw < 4) wi[nw++] = i; }
            else                        { if (nb < 4) bi[nb++] = i; }
        }
        x  = d_in[xi];
        Wk = d_in[wi[0]]; Wp = d_in[wi[1]]; Wq = d_in[wi[2]]; Wv = d_in[wi[3]];
        bk = d_in[bi[0]]; bp = d_in[bi[1]]; bq = d_in[bi[2]]; bv = d_in[bi[3]];
    }

    float*  out = (float*)d_out;     // fp32 output
    ushort* ws  = (ushort*)d_ws;

    const size_t tsz_b = (size_t)NN * CC;
    int BC = 8;
    while (BC > 1 && (size_t)BC * tsz_b * 2 * 3 > ws_size) BC >>= 1;
    ushort* k_ws = ws;
    ushort* v_ws = ws + (size_t)BC * tsz_b;
    ushort* q_ws = ws + 2 * (size_t)BC * tsz_b;

    const size_t base_bytes = (size_t)3 * BC * tsz_b * 2;
    const size_t po_elems   = (size_t)2 * NB * (NN / 256) * 256 * 256;
    const size_t ml_elems   = (size_t)2 * NB * (NN / 256) * 512;
    const int nsplit = (BC == 8 &&
                        ws_size >= base_bytes + (po_elems + ml_elems) * 4) ? 2 : 1;
    float* po = (float*)(ws + 3 * (size_t)BC * tsz_b);
    float* ml = po + po_elems;

    for (int c0 = 0; c0 < NB; c0 += BC) {
        projkvpq<<<dim3(NN / 64, CC / 64, BC), dim3(256), 0, stream>>>(
            x, Wk, bk, Wv, bv, Wp, bp, Wq, bq, k_ws, v_ws, q_ws, out, c0);
        attn_mfma<<<dim3(NN / 256, BC, nsplit), dim3(512), 0, stream>>>(
            q_ws, k_ws, v_ws, out, po, ml, c0, nsplit);
        if (nsplit == 2)
            attn_merge<<<dim3(NN / 256, BC), dim3(256), 0, stream>>>(
                po, ml, out, c0);
    }
}